// Round 1
// 510.751 us; speedup vs baseline: 1.3102x; 1.3102x over previous
//
#include <hip/hip_runtime.h>
#include <hip/hip_fp16.h>
#include <math.h>

#define BDIM 256
constexpr int Bb   = 8;
constexpr int C    = 512;
constexpr int T    = 4;
constexpr int HW   = 64 * 64;    // 4096
constexpr int NSP  = 100;
constexpr int DOUT = 128;
constexpr int PB   = 128;        // pixels per block
constexpr int KB   = 32;         // K chunk (channels per chunk)
constexpr int NCH  = C / KB;     // 16 chunks
constexpr int AST  = KB + 4;     // 36 halves: A-tile row stride (2-way-free reads)
constexpr int BST  = DOUT + 4;   // 132 f32: bins row stride (bank-spread scatter)
constexpr int PLANE = T * HW;    // 16384 floats between channels

typedef _Float16 f16;
typedef _Float16 f16x4 __attribute__((ext_vector_type(4)));
typedef _Float16 f16x8 __attribute__((ext_vector_type(8)));
typedef float    f32x4 __attribute__((ext_vector_type(4)));

// --------------- K0: zero the fp32 accumulator S (3200 x 128) ---------------
__global__ __launch_bounds__(BDIM) void zero_ws(float* __restrict__ S) {
    int i = blockIdx.x * BDIM + threadIdx.x;        // grid covers exactly 102400 f4
    ((float4*)S)[i] = float4{0.f, 0.f, 0.f, 0.f};
}

// ---- K1: fused FC (512->128, f16 MFMA) + segment-sum scatter over d=128 ----
// grid = 32 bt * 32 pixel-chunks = 1024 blocks, 4 waves (2x2: p-half x d-half).
// Wave tile 64p x 64d, per-wave acc = 4x4 f32x4 fragments.
// A = maps^T staged to LDS as f16 [p][c] (stride 36, XOR-swizzled groups);
// B = W rows gathered directly from global (L2-resident), cvt to f16 in regs.
// Y[p][d] fragments scattered into bins[id[p]][d] with LDS float atomics
// (lane groups add 16 consecutive d -> near-conflict-free), then bins flushed
// to S[bt*100+n][d] with global f32 atomics. 1/cnt cancels in the final
// L2-normalize, so no counts are needed at all.
__global__ __launch_bounds__(BDIM, 2) void fc_scatter_kernel(
    const float* __restrict__ maps,   // (B,C,T,H,W) fp32
    const int*   __restrict__ mask,   // (B,T,H,W) int32
    const float* __restrict__ Wfc,    // (128, 512) fp32
    float*       __restrict__ S)      // (B*T*NSP, 128) fp32 accumulator
{
    __shared__ __half Al[PB * AST];   // 9216 B
    __shared__ float  bins[NSP * BST];// 52800 B
    __shared__ int    ids[PB];        // 512 B   (total 62.5 KB -> 2 blocks/CU)

    const int tid = threadIdx.x;
    const int l   = tid & 63;
    const int wv  = tid >> 6;
    const int wp  = wv >> 1;          // p-half of block tile
    const int wd  = wv & 1;           // d-half of block tile
    const int lg  = l >> 4;           // k-group 0..3
    const int le  = l & 15;

    const int bid = blockIdx.x;
    const int pc  = bid & 31;         // pixel chunk
    const int bt  = bid >> 5;         // b*T + t
    const int b   = bt >> 2, t = bt & 3;
    const int p0  = pc * PB;

    for (int e = tid; e < NSP * BST; e += BDIM) bins[e] = 0.f;
    if (tid < PB) ids[tid] = mask[(size_t)bt * HW + p0 + tid];

    const float* mbase = maps + ((size_t)b * C * T + t) * HW + p0;

    // ---- staging helpers ----
    // A: per chunk, thread handles 2 (c-pair, p-quad) cells:
    //   pi = i*256+tid -> cp = pi>>5 (16 c-pairs), q = pi&31 (32 p-quads).
    // Loads are coalesced along p (float4); writes pack (c,c+1) into __half2
    // at half2-slot cp ^ (((q>>2)&3)<<2)  (XOR swizzle -> ~2-way writes).
    float4 ra[2][4];
    auto loadA = [&](int kc, float4* r) {
        const int c0 = kc * KB;
#pragma unroll
        for (int i = 0; i < 2; i++) {
            int pi = i * BDIM + tid;
            int cp = pi >> 5, q = pi & 31;
            const float* src = mbase + (size_t)(c0 + 2 * cp) * PLANE + 4 * q;
            r[2 * i]     = *(const float4*)src;
            r[2 * i + 1] = *(const float4*)(src + PLANE);
        }
    };
    auto storeA = [&](const float4* r) {
#pragma unroll
        for (int i = 0; i < 2; i++) {
            int pi = i * BDIM + tid;
            int cp = pi >> 5, q = pi & 31;
            int slot = cp ^ (((q >> 2) & 3) << 2);
#pragma unroll
            for (int j = 0; j < 4; j++) {
                __half2 h = __floats2half2_rn(((const float*)&r[2 * i])[j],
                                              ((const float*)&r[2 * i + 1])[j]);
                *(__half2*)&Al[(size_t)(4 * q + j) * AST + 2 * slot] = h;
            }
        }
    };

    // B: W rows gathered per lane (8 consecutive c = this lane's k-run)
    float4 rb[8];
    auto loadB = [&](int kc) {
        const int cb = kc * KB + 8 * lg;
#pragma unroll
        for (int dt = 0; dt < 4; dt++) {
            int d = wd * 64 + dt * 16 + le;
            const float* src = Wfc + (size_t)d * C + cb;
            rb[2 * dt]     = *(const float4*)src;
            rb[2 * dt + 1] = *(const float4*)(src + 4);
        }
    };
    f16x8 bf[4];
    auto cvtB = [&]() {
#pragma unroll
        for (int dt = 0; dt < 4; dt++) {
            f16x8 v;
#pragma unroll
            for (int j = 0; j < 4; j++) {
                v[j]     = (f16)((const float*)&rb[2 * dt])[j];
                v[j + 4] = (f16)((const float*)&rb[2 * dt + 1])[j];
            }
            bf[dt] = v;
        }
    };

    // ---- K-loop: 16 chunks of K=32, 2-deep A prefetch, 1-deep B prefetch ----
    f32x4 acc[4][4] = {};             // [pt][dt]
    loadA(0, ra[0]);
    loadB(0);
    loadA(1, ra[1]);

    for (int kc = 0; kc < NCH; kc++) {
        storeA(ra[kc & 1]);
        if (kc + 2 < NCH) loadA(kc + 2, ra[kc & 1]);
        cvtB();                        // consume rb (chunk kc)
        if (kc + 1 < NCH) loadB(kc + 1);
        __syncthreads();
#pragma unroll
        for (int pt = 0; pt < 4; pt++) {
            int p_loc = wp * 64 + pt * 16 + le;
            int g2 = lg ^ (pt & 3);    // undo write-side XOR swizzle
            const __half* ap = &Al[(size_t)p_loc * AST + 8 * g2];
            f16x4 a0 = *(const f16x4*)ap;
            f16x4 a1 = *(const f16x4*)(ap + 4);
            f16x8 af = __builtin_shufflevector(a0, a1, 0, 1, 2, 3, 4, 5, 6, 7);
#pragma unroll
            for (int dt = 0; dt < 4; dt++)
                acc[pt][dt] = __builtin_amdgcn_mfma_f32_16x16x32_f16(
                    af, bf[dt], acc[pt][dt], 0, 0, 0);
        }
        __syncthreads();
    }

    // ---- scatter Y fragments into bins: 16-lane groups add 16 consecutive d
    // (bank-spread by BST=132); only 16.8M atomic lanes kernel-wide.
#pragma unroll
    for (int pt = 0; pt < 4; pt++) {
#pragma unroll
        for (int r = 0; r < 4; r++) {
            int p_loc = wp * 64 + pt * 16 + lg * 4 + r;  // C/D row mapping
            int n = ids[p_loc];
            float* bp = &bins[n * BST + wd * 64 + le];   // C/D col mapping
#pragma unroll
            for (int dt = 0; dt < 4; dt++)
                unsafeAtomicAdd(bp + dt * 16, acc[pt][dt][r]);
        }
    }
    __syncthreads();

    // ---- flush bins -> global S (skip exact-zero bins: ~28% empty) ----
    float* Srow = S + (size_t)bt * NSP * DOUT;
    for (int e = tid; e < NSP * DOUT; e += BDIM) {
        float v = bins[(e >> 7) * BST + (e & 127)];
        if (v != 0.f) unsafeAtomicAdd(&Srow[e], v);
    }
}

// --------- K2: per-row L2 normalize (cnt cancels) + transpose store ---------
__global__ __launch_bounds__(BDIM) void norm_kernel(
    const float* __restrict__ S,      // (3200, 128)
    float*       __restrict__ out)    // (B, 128, T, NSP)
{
    const int tid = threadIdx.x, l = tid & 63, wv = tid >> 6;
    const int row = blockIdx.x * 4 + wv;              // 0..3199
    float v0 = S[(size_t)row * DOUT + l];
    float v1 = S[(size_t)row * DOUT + 64 + l];
    float ss = v0 * v0 + v1 * v1;
#pragma unroll
    for (int off = 32; off; off >>= 1) ss += __shfl_xor(ss, off, 64);
    float inv = 1.f / fmaxf(sqrtf(ss), 1e-12f);
    int n = row % NSP, bt = row / NSP;
    int b = bt >> 2, t = bt & 3;
    out[(((size_t)b * DOUT + l) * T + t) * NSP + n]      = v0 * inv;
    out[(((size_t)b * DOUT + l + 64) * T + t) * NSP + n] = v1 * inv;
}

extern "C" void kernel_launch(void* const* d_in, const int* in_sizes, int n_in,
                              void* d_out, int out_size, void* d_ws, size_t ws_size,
                              hipStream_t stream) {
    // Identify inputs by SIZE RANK (robust to ordering):
    // maps (67.1M el) > sp_mask (131K el) > W_fc (65.5K el) > scalar (1).
    int iMaps = 0, iMask = 1, iW = 2;
    {
        long best = -1;
        for (int i = 0; i < n_in; i++)
            if ((long)in_sizes[i] > best) { best = in_sizes[i]; iMaps = i; }
        long b2 = -1;
        for (int i = 0; i < n_in; i++)
            if (i != iMaps && (long)in_sizes[i] > b2) { b2 = in_sizes[i]; iMask = i; }
        long b3 = -1;
        for (int i = 0; i < n_in; i++)
            if (i != iMaps && i != iMask && (long)in_sizes[i] > b3) { b3 = in_sizes[i]; iW = i; }
    }
    const float* maps = (const float*)d_in[iMaps];  // fp32
    const int*   mask = (const int*)d_in[iMask];    // int32
    const float* Wfc  = (const float*)d_in[iW];     // fp32
    float*       out  = (float*)d_out;              // fp32
    float*       S    = (float*)d_ws;               // 3200*128 fp32 = 1.64 MB

    const dim3 blk(BDIM);
    // K0: 3200*128 floats = 102400 float4 = 400 * 256
    zero_ws<<<dim3(400), blk, 0, stream>>>(S);
    // K1: 32 bt * 32 pixel-chunks
    fc_scatter_kernel<<<dim3(Bb * T * (HW / PB)), blk, 0, stream>>>(maps, mask, Wfc, S);
    // K2: 3200 rows / 4 rows-per-block
    norm_kernel<<<dim3(Bb * T * NSP / 4), blk, 0, stream>>>(S, out);
}